// Round 1
// 1200.450 us; speedup vs baseline: 1.1757x; 1.1757x over previous
//
#include <hip/hip_runtime.h>
#include <cstdint>
#include <cstddef>

// ---------------------------------------------------------------------------
// MultiLayer bidirectional TreeLSTM, N=4096 heap tree, H=512, L=2.
// R7: GEMM core rebuilt on global_load_lds (16B DMA staging, m97/m151 lever)
// + minimum 2-phase LDS double-buffer (T3-minimum template, one barrier per
// K-step, prefetch of tile t+1 overlaps MFMA of tile t). LDS linear stride
// 32 f16 (DMA requires contiguous dest). elem_merged vectorized to f16x8 /
// float4 (8 elems/lane, G13). Structure of the launch chain unchanged
// (R6 merged fwd/bwd stages). Workspace ~121 MB.
// ---------------------------------------------------------------------------

#define HDIM 512
#define ZROW 4096
#define NCAT 6656   // 512 px_f | 3072 x2_f | 512 px_b | 2560 x2_b

typedef _Float16 f16;
typedef f16   f16x8 __attribute__((ext_vector_type(8)));
typedef float f32x4 __attribute__((ext_vector_type(4)));

__device__ __forceinline__ float sigm(float x) { return 1.0f / (1.0f + expf(-x)); }

// direct global->LDS DMA, 16 B per lane. LDS dest = wave-uniform base +
// lane*16 (we pass base + lane*16 so lane 0's value is the wave base).
__device__ __forceinline__ void glds16(const f16* g, f16* l)
{
    __builtin_amdgcn_global_load_lds(
        (const __attribute__((address_space(1))) void*)g,
        (__attribute__((address_space(3))) void*)l,
        16, 0, 0);
}

__global__ __launch_bounds__(256) void cvt16(
    const float* __restrict__ s, f16* __restrict__ d, int n8)
{
    int i = blockIdx.x * 256 + threadIdx.x;
    if (i >= n8) return;
    float4 v0 = ((const float4*)s)[(size_t)i * 2];
    float4 v1 = ((const float4*)s)[(size_t)i * 2 + 1];
    f16x8 o;
    o[0] = (f16)v0.x; o[1] = (f16)v0.y; o[2] = (f16)v0.z; o[3] = (f16)v0.w;
    o[4] = (f16)v1.x; o[5] = (f16)v1.y; o[6] = (f16)v1.z; o[7] = (f16)v1.w;
    *(f16x8*)(d + (size_t)i * 8) = o;
}

// concat Wl|Wr along K: dst[3072][1024] f16
__global__ __launch_bounds__(256) void cvt16_lr(
    const float* __restrict__ Wl, const float* __restrict__ Wr, f16* __restrict__ d)
{
    int i = blockIdx.x * 256 + threadIdx.x;   // over 3072*1024/8
    int col8 = (i * 8) & 1023;
    int row  = (i * 8) >> 10;
    const float* s = (col8 < HDIM) ? (Wl + (size_t)row * HDIM + col8)
                                   : (Wr + (size_t)row * HDIM + col8 - HDIM);
    float4 v0 = ((const float4*)s)[0];
    float4 v1 = ((const float4*)s)[1];
    f16x8 o;
    o[0] = (f16)v0.x; o[1] = (f16)v0.y; o[2] = (f16)v0.z; o[3] = (f16)v0.w;
    o[4] = (f16)v1.x; o[5] = (f16)v1.y; o[6] = (f16)v1.z; o[7] = (f16)v1.w;
    *(f16x8*)(d + (size_t)i * 8) = o;
}

__global__ __launch_bounds__(256) void biascat_k(
    const float* __restrict__ a, const float* __restrict__ b,
    const float* __restrict__ c, const float* __restrict__ dd,
    float* __restrict__ o)
{
    int t = blockIdx.x * 256 + threadIdx.x;
    if (t >= NCAT) return;
    float v;
    if (t < 512) v = a[t];
    else if (t < 3584) v = b[t - 512];
    else if (t < 4096) v = c[t - 3584];
    else v = dd[t - 4096];
    o[t] = v;
}

__global__ void zero_slots(f16* H, float* cbf, float* cbb)
{
    int t = threadIdx.x;  // 1024 threads
    H[(size_t)ZROW * 1024 + t] = (f16)0.0f;
    if (t < HDIM) {
        cbf[(size_t)ZROW * HDIM + t] = 0.0f;
        cbb[(size_t)ZROW * HDIM + t] = 0.0f;
    }
}

// ---------------------------------------------------------------------------
// Precompute GEMM: C[M,N] = A[M,K] @ W[N,K]^T + bias, f16 in, f32 acc, f16 out.
// 128x128 tile, 4 waves (2x2), each wave 4x4 MFMA 16x16x32 tiles, BK=32.
// Staging: global_load_lds dwordx4. Per K-step, tile = 128 rows x 32 f16
// = 8 KB = 8 chunks of 1 KB; wave w DMAs chunks {w, w+4}; lane l covers
// row c*16 + (l>>2), 16B segment (l&3) -> LDS linear f16 idx c*512 + l*8.
// 2-phase double buffer: stage tile t+1, compute tile t, one barrier/step.
// ---------------------------------------------------------------------------
__global__ __launch_bounds__(256) void mm_pre(
    const f16* __restrict__ A, const f16* __restrict__ W,
    const float* __restrict__ bias, f16* __restrict__ C, int N, int K)
{
    __shared__ __align__(16) f16 Ab[2][128 * 32];
    __shared__ __align__(16) f16 Bb[2][128 * 32];
    const int t  = threadIdx.x;
    const int L  = t & 63;
    const int w  = t >> 6;
    const int wm = (w & 1) << 6;
    const int wn = (w >> 1) << 6;
    const int fr = L & 15;
    const int fq = L >> 4;
    const int la  = L >> 2;        // row within 16-row chunk
    const int ls8 = (L & 3) << 3;  // f16 offset of this lane's 16B segment

    const f16* a0 = A + (size_t)(blockIdx.y * 128 + w * 16 + la) * K + ls8;
    const f16* a1 = a0 + (size_t)64 * K;
    const f16* b0 = W + (size_t)(blockIdx.x * 128 + w * 16 + la) * K + ls8;
    const f16* b1 = b0 + (size_t)64 * K;
    const int lo = w * 512 + L * 8;   // chunk w   (f16 idx in buffer)
    const int hi = lo + 2048;         // chunk w+4

    f32x4 acc[4][4] = {};
    const int nt = K >> 5;

#define STG_P(sel, k0)                       \
    do {                                     \
        glds16(a0 + (k0), &Ab[sel][lo]);     \
        glds16(a1 + (k0), &Ab[sel][hi]);     \
        glds16(b0 + (k0), &Bb[sel][lo]);     \
        glds16(b1 + (k0), &Bb[sel][hi]);     \
    } while (0)

    STG_P(0, 0);
    __syncthreads();                  // drains vmcnt(0): buf0 ready
    int cur = 0;
    for (int tt = 0; tt < nt; ++tt) {
        if (tt + 1 < nt) STG_P(cur ^ 1, (tt + 1) << 5);
        f16x8 af[4], bg[4];
#pragma unroll
        for (int i = 0; i < 4; ++i)
            af[i] = *(const f16x8*)(&Ab[cur][(wm + i * 16 + fr) * 32 + fq * 8]);
#pragma unroll
        for (int j = 0; j < 4; ++j)
            bg[j] = *(const f16x8*)(&Bb[cur][(wn + j * 16 + fr) * 32 + fq * 8]);
#pragma unroll
        for (int i = 0; i < 4; ++i)
#pragma unroll
            for (int j = 0; j < 4; ++j)
                acc[i][j] = __builtin_amdgcn_mfma_f32_16x16x32_f16(
                    af[i], bg[j], acc[i][j], 0, 0, 0);
        __syncthreads();              // drains vmcnt(0): next buf staged; LDS reads done
        cur ^= 1;
    }
#undef STG_P

    // C/D layout: col = lane&15, row = (lane>>4)*4 + reg  [m89-verified]
    const int gr0 = blockIdx.y * 128 + wm + fq * 4;
    const int gc0 = blockIdx.x * 128 + wn + fr;
#pragma unroll
    for (int j = 0; j < 4; ++j) {
        const int gc = gc0 + j * 16;
        const float bj = bias[gc];
#pragma unroll
        for (int i = 0; i < 4; ++i) {
            const int gr = gr0 + i * 16;
#pragma unroll
            for (int rr = 0; rr < 4; ++rr)
                C[(size_t)(gr + rr) * N + gc] = (f16)(acc[i][j][rr] + bj);
        }
    }
}

// ---------------------------------------------------------------------------
// Merged stage GEMM: one launch computes BOTH
//   fwd: Gf[r,0:3072] = H_f[lc]@Wl^T + H_f[rc]@Wr^T   (fm rows, K=1024)
//   bwd: Gb[r,0:2560] = H_b[par]@Wh^T                  (bm rows, K=512)
// 1D grid: first ceil(fm/128)*24 blocks are fwd tiles, rest bwd tiles.
// Same DMA-staged 2-phase core as mm_pre; A rows gathered (per-lane global
// addresses, rows >= m -> zero row). fwd K-halves pick lc/rc pointer.
// ---------------------------------------------------------------------------
__global__ __launch_bounds__(256) void mmstage(
    const f16* __restrict__ H,
    const int* __restrict__ lc, const int* __restrict__ rc,
    const int* __restrict__ par,
    int fbase, int fm, int bbase, int bm,
    const f16* __restrict__ Wlr, const f16* __restrict__ Wh,
    f16* __restrict__ Gf, f16* __restrict__ Gb)
{
    __shared__ __align__(16) f16 Ab[2][128 * 32];
    __shared__ __align__(16) f16 Bb[2][128 * 32];
    const int t  = threadIdx.x;
    const int L  = t & 63;
    const int w  = t >> 6;
    const int wm = (w & 1) << 6;
    const int wn = (w >> 1) << 6;
    const int fr = L & 15;
    const int fq = L >> 4;
    const int la  = L >> 2;
    const int ls8 = (L & 3) << 3;

    const int nfB = ((fm + 127) >> 7) * 24;
    const int bid = blockIdx.x;
    const bool isF = bid < nfB;
    int by, bx, m, N, K;
    const f16* W;
    f16* C;
    if (isF) { by = bid / 24; bx = bid - by * 24; m = fm; N = 3072; K = 1024; W = Wlr; C = Gf; }
    else     { int b2 = bid - nfB; by = b2 / 20; bx = b2 - by * 20; m = bm; N = 2560; K = 512; W = Wh; C = Gb; }

    // gather pointers for the two A rows this lane stages (chunks w, w+4)
    const int g0 = by * 128 + w * 16 + la;
    const int g1 = g0 + 64;
    const f16 *a0lo, *a0hi, *a1lo, *a1hi;
    if (isF) {
        int n1 = ZROW, n2 = ZROW, n3 = ZROW, n4 = ZROW;
        if (g0 < m) { n1 = lc[fbase + g0]; n2 = rc[fbase + g0]; }
        if (g1 < m) { n3 = lc[fbase + g1]; n4 = rc[fbase + g1]; }
        a0lo = H + (size_t)n1 * 1024 + ls8;          // left child, k < 512
        a0hi = H + (size_t)n2 * 1024 + ls8 - HDIM;   // right child, k >= 512 (+k0 folds the -512)
        a1lo = H + (size_t)n3 * 1024 + ls8;
        a1hi = H + (size_t)n4 * 1024 + ls8 - HDIM;
    } else {
        int n1 = ZROW, n3 = ZROW;
        if (g0 < m) n1 = par[bbase + g0];
        if (g1 < m) n3 = par[bbase + g1];
        a0lo = H + (size_t)n1 * 1024 + HDIM + ls8;   // bwd h of parent, K=512
        a0hi = a0lo;                                  // never selected (k0 < 512)
        a1lo = H + (size_t)n3 * 1024 + HDIM + ls8;
        a1hi = a1lo;
    }
    const f16* b0 = W + (size_t)(bx * 128 + w * 16 + la) * K + ls8;
    const f16* b1 = b0 + (size_t)64 * K;
    const int lo = w * 512 + L * 8;
    const int hi = lo + 2048;

    f32x4 acc[4][4] = {};
    const int nt = K >> 5;

#define STG_S(sel, k0)                                                      \
    do {                                                                    \
        const f16* sa0 = ((k0) < HDIM) ? (a0lo + (k0)) : (a0hi + (k0));     \
        const f16* sa1 = ((k0) < HDIM) ? (a1lo + (k0)) : (a1hi + (k0));     \
        glds16(sa0, &Ab[sel][lo]);                                          \
        glds16(sa1, &Ab[sel][hi]);                                          \
        glds16(b0 + (k0), &Bb[sel][lo]);                                    \
        glds16(b1 + (k0), &Bb[sel][hi]);                                    \
    } while (0)

    STG_S(0, 0);
    __syncthreads();
    int cur = 0;
    for (int tt = 0; tt < nt; ++tt) {
        if (tt + 1 < nt) STG_S(cur ^ 1, (tt + 1) << 5);
        f16x8 af[4], bg[4];
#pragma unroll
        for (int i = 0; i < 4; ++i)
            af[i] = *(const f16x8*)(&Ab[cur][(wm + i * 16 + fr) * 32 + fq * 8]);
#pragma unroll
        for (int j = 0; j < 4; ++j)
            bg[j] = *(const f16x8*)(&Bb[cur][(wn + j * 16 + fr) * 32 + fq * 8]);
#pragma unroll
        for (int i = 0; i < 4; ++i)
#pragma unroll
            for (int j = 0; j < 4; ++j)
                acc[i][j] = __builtin_amdgcn_mfma_f32_16x16x32_f16(
                    af[i], bg[j], acc[i][j], 0, 0, 0);
        __syncthreads();
        cur ^= 1;
    }
#undef STG_S

    const int gr0 = by * 128 + wm + fq * 4;
    const int gc0 = bx * 128 + wn + fr;
#pragma unroll
    for (int j = 0; j < 4; ++j) {
        const int gc = gc0 + j * 16;
#pragma unroll
        for (int i = 0; i < 4; ++i) {
            const int gr = gr0 + i * 16;
#pragma unroll
            for (int rr = 0; rr < 4; ++rr) {
                if (gr + rr < m)
                    C[(size_t)(gr + rr) * N + gc] = (f16)acc[i][j][rr];
            }
        }
    }
}

// ---------------------------------------------------------------------------
// Merged elementwise, vectorized 8 elems/lane (f16x8 / float4 traffic).
// fwd cells for fm nodes at fbase (+Gf if non-null) and bwd cells for bm
// nodes at bbase (+Gb if non-null). Separate cbf/cbb.
// ---------------------------------------------------------------------------
__global__ __launch_bounds__(256) void elem_merged(
    const f16* __restrict__ Gf, const f16* __restrict__ Gb,
    const f16* __restrict__ PX,
    int fbase, int fm, int bbase, int bm,
    const int* __restrict__ lc, const int* __restrict__ rc,
    const int* __restrict__ par,
    float* __restrict__ cbf, float* __restrict__ cbb,
    f16* __restrict__ H, float* __restrict__ out32,
    const float* __restrict__ bl, const float* __restrict__ br,
    const float* __restrict__ bh)
{
    int t = blockIdx.x * 256 + threadIdx.x;
    const int fvec = fm * 64;               // HDIM/8 vectors per row
    if (t < fvec) {
        int row = t >> 6, j8 = (t & 63) << 3;
        int node = fbase + row;
        const f16* pxr = PX + (size_t)node * NCAT;
        float g[6][8];
#pragma unroll
        for (int q = 0; q < 6; ++q) {
            f16x8 pv = *(const f16x8*)(pxr + HDIM + q * HDIM + j8);
            const float* blp = bl + q * HDIM + j8;
            const float* brp = br + q * HDIM + j8;
            if (Gf) {
                f16x8 gv = *(const f16x8*)(Gf + (size_t)row * 3072 + q * HDIM + j8);
#pragma unroll
                for (int e = 0; e < 8; ++e)
                    g[q][e] = (float)pv[e] + blp[e] + brp[e] + (float)gv[e];
            } else {
#pragma unroll
                for (int e = 0; e < 8; ++e)
                    g[q][e] = (float)pv[e] + blp[e] + brp[e];
            }
        }
        int lcn = lc[node], rcn = rc[node];
        const float* clp = cbf + (size_t)lcn * HDIM + j8;
        const float* crp = cbf + (size_t)rcn * HDIM + j8;
        f32x4 cl0 = *(const f32x4*)clp, cl1 = *(const f32x4*)(clp + 4);
        f32x4 cr0 = *(const f32x4*)crp, cr1 = *(const f32x4*)(crp + 4);
        f16x8 pxv = *(const f16x8*)(pxr + j8);
        f32x4 co0, co1;
        f16x8 hv;
        f32x4 ho0, ho1;
#pragma unroll
        for (int e = 0; e < 8; ++e) {
            float clv = (e < 4) ? cl0[e & 3] : cl1[e & 3];
            float crv = (e < 4) ? cr0[e & 3] : cr1[e & 3];
            float i_ = sigm(g[0][e]), o_ = sigm(g[1][e]);
            float fl_ = sigm(g[2][e]), fr_ = sigm(g[3][e]);
            float u_ = tanhf(g[4][e]), r_ = sigm(g[5][e]);
            float c  = i_ * u_ + fl_ * clv + fr_ * crv;
            float hc = o_ * tanhf(c);
            float hf = r_ * hc + (1.0f - r_) * (float)pxv[e];
            if (e < 4) { co0[e & 3] = c; ho0[e & 3] = hf; }
            else       { co1[e & 3] = c; ho1[e & 3] = hf; }
            hv[e] = (f16)hf;
        }
        float* cdst = cbf + (size_t)node * HDIM + j8;
        *(f32x4*)cdst = co0; *(f32x4*)(cdst + 4) = co1;
        *(f16x8*)(H + (size_t)node * 1024 + j8) = hv;
        if (out32) {
            float* od = out32 + (size_t)node * 1024 + j8;
            *(f32x4*)od = ho0; *(f32x4*)(od + 4) = ho1;
        }
    } else {
        int t2 = t - fvec;
        if (t2 >= bm * 64) return;
        int row = t2 >> 6, j8 = (t2 & 63) << 3;
        int node = bbase + row;
        const f16* pxr = PX + (size_t)node * NCAT;
        float g[5][8];
#pragma unroll
        for (int q = 0; q < 5; ++q) {
            f16x8 pv = *(const f16x8*)(pxr + 4096 + q * HDIM + j8);
            const float* bhp = bh + q * HDIM + j8;
            if (Gb) {
                f16x8 gv = *(const f16x8*)(Gb + (size_t)row * 2560 + q * HDIM + j8);
#pragma unroll
                for (int e = 0; e < 8; ++e)
                    g[q][e] = (float)pv[e] + bhp[e] + (float)gv[e];
            } else {
#pragma unroll
                for (int e = 0; e < 8; ++e)
                    g[q][e] = (float)pv[e] + bhp[e];
            }
        }
        int p = par[node];
        const float* cpp = cbb + (size_t)p * HDIM + j8;
        f32x4 cp0 = *(const f32x4*)cpp, cp1 = *(const f32x4*)(cpp + 4);
        f16x8 pxv = *(const f16x8*)(pxr + 3584 + j8);
        f32x4 co0, co1;
        f16x8 hv;
        f32x4 ho0, ho1;
#pragma unroll
        for (int e = 0; e < 8; ++e) {
            float cpv = (e < 4) ? cp0[e & 3] : cp1[e & 3];
            float i_ = sigm(g[0][e]), o_ = sigm(g[1][e]), f_ = sigm(g[2][e]);
            float u_ = tanhf(g[3][e]), r_ = sigm(g[4][e]);
            float c  = i_ * u_ + f_ * cpv;
            float hc = o_ * tanhf(c);
            float hf = r_ * hc + (1.0f - r_) * (float)pxv[e];
            if (e < 4) { co0[e & 3] = c; ho0[e & 3] = hf; }
            else       { co1[e & 3] = c; ho1[e & 3] = hf; }
            hv[e] = (f16)hf;
        }
        float* cdst = cbb + (size_t)node * HDIM + j8;
        *(f32x4*)cdst = co0; *(f32x4*)(cdst + 4) = co1;
        *(f16x8*)(H + (size_t)node * 1024 + HDIM + j8) = hv;
        if (out32) {
            float* od = out32 + (size_t)node * 1024 + HDIM + j8;
            *(f32x4*)od = ho0; *(f32x4*)(od + 4) = ho1;
        }
    }
}

extern "C" void kernel_launch(void* const* d_in, const int* in_sizes, int n_in,
                              void* d_out, int out_size, void* d_ws, size_t ws_size,
                              hipStream_t stream)
{
    (void)in_sizes; (void)n_in; (void)out_size; (void)ws_size;
    const float* features = (const float*)d_in[0];
    const float* fw_Wp = (const float*)d_in[1];
    const float* fw_bp = (const float*)d_in[2];
    const float* fw_Wx = (const float*)d_in[3];
    const float* fw_bx = (const float*)d_in[4];
    const float* fw_Wl = (const float*)d_in[5];
    const float* fw_bl = (const float*)d_in[6];
    const float* fw_Wr = (const float*)d_in[7];
    const float* fw_br = (const float*)d_in[8];
    const float* bw_Wp = (const float*)d_in[9];
    const float* bw_bp = (const float*)d_in[10];
    const float* bw_Wx = (const float*)d_in[11];
    const float* bw_bx = (const float*)d_in[12];
    const float* bw_Wh = (const float*)d_in[13];
    const float* bw_bh = (const float*)d_in[14];
    const int* lc  = (const int*)d_in[17];
    const int* rc  = (const int*)d_in[18];
    const int* par = (const int*)d_in[19];

    // workspace layout (f16 units unless noted), ~121 MB.
    // Gf ALIASES feat16: feat16 is only read by the layer-0 precompute, which
    // completes (stream order) before the first mmstage writes Gf.
    f16* feat16 = (f16*)d_ws;                       // 4096*1024
    f16* Gf     = feat16;                           // 1024*3072 <= 4096*1024
    f16* H      = feat16 + (size_t)4096 * 1024;     // 4097*1024
    f16* Wcat   = H     + (size_t)4097 * 1024;      // 6656*1024
    f16* Wlr    = Wcat  + (size_t)NCAT * 1024;      // 3072*1024
    f16* Wh     = Wlr   + (size_t)3072 * 1024;      // 2560*512
    f16* PX     = Wh    + (size_t)2560 * 512;       // 4096*6656
    f16* Gb     = PX    + (size_t)4096 * NCAT;      // 2048*2560
    float* biascat = (float*)(Gb + (size_t)2048 * 2560);
    float* cbf     = biascat + NCAT;                // 4097*512 f32
    float* cbb     = cbf + (size_t)4097 * HDIM;     // 4097*512 f32

    zero_slots<<<dim3(1), dim3(1024), 0, stream>>>(H, cbf, cbb);
    cvt16<<<dim3(2048), 256, 0, stream>>>(features, feat16, 4096 * 1024 / 8);

    // stage schedule (per layer): merged launch i pairs fwd stage i with bwd
    // stage i. fwd: special node 2047, then levels 10..0. bwd: levels 1..12.
    static const int fb[12] = {2047, 1023, 511, 255, 127, 63, 31, 15, 7, 3, 1, 0};
    static const int fmv[12] = {1, 1024, 512, 256, 128, 64, 32, 16, 8, 4, 2, 1};
    static const int bb[12] = {1, 3, 7, 15, 31, 63, 127, 255, 511, 1023, 2047, 4095};
    static const int bmv[12] = {2, 4, 8, 16, 32, 64, 128, 256, 512, 1024, 2048, 1};

    for (int l = 0; l < 2; ++l) {
        cvt16<<<dim3(256),  256, 0, stream>>>(fw_Wp + (size_t)l * 512 * 1024,  Wcat,               512 * 1024 / 8);
        cvt16<<<dim3(1536), 256, 0, stream>>>(fw_Wx + (size_t)l * 3072 * 1024, Wcat + 512 * 1024,  3072 * 1024 / 8);
        cvt16<<<dim3(256),  256, 0, stream>>>(bw_Wp + (size_t)l * 512 * 1024,  Wcat + 3584 * 1024, 512 * 1024 / 8);
        cvt16<<<dim3(1280), 256, 0, stream>>>(bw_Wx + (size_t)l * 2560 * 1024, Wcat + (size_t)4096 * 1024, 2560 * 1024 / 8);
        cvt16_lr<<<dim3(1536), 256, 0, stream>>>(fw_Wl + (size_t)l * 3072 * 512,
                                                 fw_Wr + (size_t)l * 3072 * 512, Wlr);
        cvt16<<<dim3(640), 256, 0, stream>>>(bw_Wh + (size_t)l * 2560 * 512, Wh, 2560 * 512 / 8);
        biascat_k<<<dim3(26), 256, 0, stream>>>(fw_bp + (size_t)l * 512, fw_bx + (size_t)l * 3072,
                                                bw_bp + (size_t)l * 512, bw_bx + (size_t)l * 2560, biascat);

        // fused precompute: PX[4096][6656] = A @ [Wp_f|Wx_f|Wp_b|Wx_b]^T + bias
        const f16* A16 = (l == 0) ? feat16 : H;
        mm_pre<<<dim3(NCAT / 128, 4096 / 128), 256, 0, stream>>>(
            A16, Wcat, biascat, PX, NCAT, 1024);

        float* o32 = (l == 1) ? (float*)d_out : nullptr;
        const float* bl_l = fw_bl + (size_t)l * 3072;
        const float* br_l = fw_br + (size_t)l * 3072;
        const float* bh_l = bw_bh + (size_t)l * 2560;

        // merged leaves (fwd, m=2048) + root (bwd, m=1): no GEMM needed
        {
            int tot = (2048 + 1) * 64;
            elem_merged<<<dim3((tot + 255) / 256), 256, 0, stream>>>(
                nullptr, nullptr, PX, 2048, 2048, 0, 1,
                lc, rc, par, cbf, cbb, H, o32, bl_l, br_l, bh_l);
        }
        for (int i = 0; i < 12; ++i) {
            int nfB = ((fmv[i] + 127) >> 7) * 24;
            int nbB = ((bmv[i] + 127) >> 7) * 20;
            mmstage<<<dim3(nfB + nbB), 256, 0, stream>>>(
                H, lc, rc, par, fb[i], fmv[i], bb[i], bmv[i], Wlr, Wh, Gf, Gb);
            int tot = (fmv[i] + bmv[i]) * 64;
            elem_merged<<<dim3((tot + 255) / 256), 256, 0, stream>>>(
                Gf, Gb, PX, fb[i], fmv[i], bb[i], bmv[i],
                lc, rc, par, cbf, cbb, H, o32, bl_l, br_l, bh_l);
        }
    }
    // layer-1 elems wrote d_out directly; nothing else to copy
}

// Round 2
// 838.057 us; speedup vs baseline: 1.6840x; 1.4324x over previous
//
#include <hip/hip_runtime.h>
#include <cstdint>
#include <cstddef>

// ---------------------------------------------------------------------------
// MultiLayer bidirectional TreeLSTM, N=4096 heap tree, H=512, L=2.
// R8: (1) stage GEMM + elementwise FUSED into one kernel (stage_fused) via
// gate-interleaved weight layout (fwd n'=j*6+q BN=96, bwd n'=j*5+q BN=80):
// each block owns all gates for a 16-wide j-span -> epilogue applies LSTM
// cell math in-block, writes H/cbf/cbb directly. No Gf/Gb round-trip, 24
// launches removed, BK=64 halves K-iterations (latency chain).
// (2) LDS read swizzle (rule #21: linear LDS dest, inverse-swizzled GLOBAL
// source seg, swizzled ds_read) -> frag reads 8/16-way -> 2-way conflicts.
// mm_pre keeps BK=32 (occupancy) + gains the swizzle. Workspace ~113 MB.
// ---------------------------------------------------------------------------

#define HDIM 512
#define ZROW 4096
#define NCAT 6656   // 512 px_f | 3072 x2_f | 512 px_b | 2560 x2_b

typedef _Float16 f16;
typedef f16   f16x8 __attribute__((ext_vector_type(8)));
typedef float f32x4 __attribute__((ext_vector_type(4)));

__device__ __forceinline__ float sigm(float x) { return 1.0f / (1.0f + expf(-x)); }

// direct global->LDS DMA, 16 B per lane; LDS dest linear (base + lane*16).
__device__ __forceinline__ void glds16(const f16* g, f16* l)
{
    __builtin_amdgcn_global_load_lds(
        (const __attribute__((address_space(1))) void*)g,
        (__attribute__((address_space(3))) void*)l,
        16, 0, 0);
}

__global__ __launch_bounds__(256) void cvt16(
    const float* __restrict__ s, f16* __restrict__ d, int n8)
{
    int i = blockIdx.x * 256 + threadIdx.x;
    if (i >= n8) return;
    float4 v0 = ((const float4*)s)[(size_t)i * 2];
    float4 v1 = ((const float4*)s)[(size_t)i * 2 + 1];
    f16x8 o;
    o[0] = (f16)v0.x; o[1] = (f16)v0.y; o[2] = (f16)v0.z; o[3] = (f16)v0.w;
    o[4] = (f16)v1.x; o[5] = (f16)v1.y; o[6] = (f16)v1.z; o[7] = (f16)v1.w;
    *(f16x8*)(d + (size_t)i * 8) = o;
}

// concat Wl|Wr along K AND permute rows gate-interleaved: src row n (q=n>>9,
// j=n&511) -> dst row j*6+q. dst[3072][1024] f16.
__global__ __launch_bounds__(256) void cvt16_lr(
    const float* __restrict__ Wl, const float* __restrict__ Wr, f16* __restrict__ d)
{
    int i = blockIdx.x * 256 + threadIdx.x;   // over 3072*1024/8
    int col8 = (i * 8) & 1023;
    int row  = (i * 8) >> 10;
    const float* s = (col8 < HDIM) ? (Wl + (size_t)row * HDIM + col8)
                                   : (Wr + (size_t)row * HDIM + col8 - HDIM);
    float4 v0 = ((const float4*)s)[0];
    float4 v1 = ((const float4*)s)[1];
    f16x8 o;
    o[0] = (f16)v0.x; o[1] = (f16)v0.y; o[2] = (f16)v0.z; o[3] = (f16)v0.w;
    o[4] = (f16)v1.x; o[5] = (f16)v1.y; o[6] = (f16)v1.z; o[7] = (f16)v1.w;
    int np = (row & 511) * 6 + (row >> 9);
    *(f16x8*)(d + (size_t)np * 1024 + col8) = o;
}

// Wh permute: src row n (2560 rows, K=512): dst row j*5+q.
__global__ __launch_bounds__(256) void cvt16_perm5(
    const float* __restrict__ s, f16* __restrict__ d)
{
    int i = blockIdx.x * 256 + threadIdx.x;   // over 2560*512/8
    int col8 = (i * 8) & 511;
    int row  = (i * 8) >> 9;
    float4 v0 = ((const float4*)(s + (size_t)row * HDIM + col8))[0];
    float4 v1 = ((const float4*)(s + (size_t)row * HDIM + col8))[1];
    f16x8 o;
    o[0] = (f16)v0.x; o[1] = (f16)v0.y; o[2] = (f16)v0.z; o[3] = (f16)v0.w;
    o[4] = (f16)v1.x; o[5] = (f16)v1.y; o[6] = (f16)v1.z; o[7] = (f16)v1.w;
    int np = (row & 511) * 5 + (row >> 9);
    *(f16x8*)(d + (size_t)np * HDIM + col8) = o;
}

__global__ __launch_bounds__(256) void biascat_k(
    const float* __restrict__ a, const float* __restrict__ b,
    const float* __restrict__ c, const float* __restrict__ dd,
    float* __restrict__ o)
{
    int t = blockIdx.x * 256 + threadIdx.x;
    if (t >= NCAT) return;
    float v;
    if (t < 512) v = a[t];
    else if (t < 3584) v = b[t - 512];
    else if (t < 4096) v = c[t - 3584];
    else v = dd[t - 4096];
    o[t] = v;
}

__global__ void zero_slots(f16* H, float* cbf, float* cbb)
{
    int t = threadIdx.x;  // 1024 threads
    H[(size_t)ZROW * 1024 + t] = (f16)0.0f;
    if (t < HDIM) {
        cbf[(size_t)ZROW * HDIM + t] = 0.0f;
        cbb[(size_t)ZROW * HDIM + t] = 0.0f;
    }
}

// ---------------------------------------------------------------------------
// Precompute GEMM: C[M,N] = A[M,K] @ W[N,K]^T + bias, f16 in, f32 acc, f16 out.
// 128x128 tile, 4 waves (2x2), 4x4 MFMA 16x16x32 per wave, BK=32.
// glds 16B staging, 2-phase dbuf. Swizzle: row's 4 16B-slots stored at
// slot ^ ((row>>1)&3) (via pre-swizzled global source col); frag reads use
// the same XOR -> 2-way bank aliasing only (free).
// ---------------------------------------------------------------------------
__global__ __launch_bounds__(256) void mm_pre(
    const f16* __restrict__ A, const f16* __restrict__ W,
    const float* __restrict__ bias, f16* __restrict__ C, int N, int K)
{
    __shared__ __align__(16) f16 Ab[2][128 * 32];
    __shared__ __align__(16) f16 Bb[2][128 * 32];
    const int t  = threadIdx.x;
    const int L  = t & 63;
    const int w  = t >> 6;
    const int wm = (w & 1) << 6;
    const int wn = (w >> 1) << 6;
    const int fr = L & 15;
    const int fq = L >> 4;
    const int la  = L >> 2;                              // row within 16-row chunk
    const int cs  = (((L & 3) ^ ((L >> 3) & 3)) << 3);   // swizzled source col (f16)

    const f16* a0 = A + (size_t)(blockIdx.y * 128 + w * 16 + la) * K + cs;
    const f16* a1 = a0 + (size_t)64 * K;
    const f16* b0 = W + (size_t)(blockIdx.x * 128 + w * 16 + la) * K + cs;
    const f16* b1 = b0 + (size_t)64 * K;
    const int lo = w * 512 + L * 8;   // chunk w   (f16 idx in buffer)
    const int hi = lo + 2048;         // chunk w+4

    f32x4 acc[4][4] = {};
    const int nt = K >> 5;

#define STG_P(sel, k0)                       \
    do {                                     \
        glds16(a0 + (k0), &Ab[sel][lo]);     \
        glds16(a1 + (k0), &Ab[sel][hi]);     \
        glds16(b0 + (k0), &Bb[sel][lo]);     \
        glds16(b1 + (k0), &Bb[sel][hi]);     \
    } while (0)

    STG_P(0, 0);
    __syncthreads();
    int cur = 0;
    const int fsw = ((fr >> 1) & 3) << 3;   // frag-read swizzle (f16 units)
    for (int tt = 0; tt < nt; ++tt) {
        if (tt + 1 < nt) STG_P(cur ^ 1, (tt + 1) << 5);
        f16x8 af[4], bg[4];
#pragma unroll
        for (int i = 0; i < 4; ++i)
            af[i] = *(const f16x8*)(&Ab[cur][(wm + i * 16 + fr) * 32 + ((fq << 3) ^ fsw)]);
#pragma unroll
        for (int j = 0; j < 4; ++j)
            bg[j] = *(const f16x8*)(&Bb[cur][(wn + j * 16 + fr) * 32 + ((fq << 3) ^ fsw)]);
#pragma unroll
        for (int i = 0; i < 4; ++i)
#pragma unroll
            for (int j = 0; j < 4; ++j)
                acc[i][j] = __builtin_amdgcn_mfma_f32_16x16x32_f16(
                    af[i], bg[j], acc[i][j], 0, 0, 0);
        __syncthreads();
        cur ^= 1;
    }
#undef STG_P

    // C/D layout: col = lane&15, row = (lane>>4)*4 + reg  [m89-verified]
    const int gr0 = blockIdx.y * 128 + wm + fq * 4;
    const int gc0 = blockIdx.x * 128 + wn + fr;
#pragma unroll
    for (int j = 0; j < 4; ++j) {
        const int gc = gc0 + j * 16;
        const float bj = bias[gc];
#pragma unroll
        for (int i = 0; i < 4; ++i) {
            const int gr = gr0 + i * 16;
#pragma unroll
            for (int rr = 0; rr < 4; ++rr)
                C[(size_t)(gr + rr) * N + gc] = (f16)(acc[i][j][rr] + bj);
        }
    }
}

// ---------------------------------------------------------------------------
// Fused stage kernel: GEMM (gathered A rows) + LSTM cell math + H/c writes,
// one launch per merged fwd/bwd stage pair.
//   fwd blocks: 128 rows x 96 cols (j-span 16, all 6 gates), K=1024, BK=64
//   bwd blocks: 128 rows x 80 cols (j-span 16, all 5 gates), K=512,  BK=64
// LDS: staging Ab[2][128*64] + Bb[2][96*64] (56 KB max), reused as f32
// scoreboard Sg (padded stride 100/84) for the gate-major epilogue.
// Swizzle: per-row 8 16B-slots at slot ^ (row&7) via pre-swizzled source.
// ---------------------------------------------------------------------------
__global__ __launch_bounds__(256) void stage_fused(
    const f16* __restrict__ Wlr, const f16* __restrict__ Wh,
    f16* H, const f16* __restrict__ PX,
    const int* __restrict__ lc, const int* __restrict__ rc,
    const int* __restrict__ par,
    int fbase, int fm, int bbase, int bm,
    float* __restrict__ cbf, float* __restrict__ cbb,
    float* out32,
    const float* __restrict__ bl, const float* __restrict__ br,
    const float* __restrict__ bh)
{
    __shared__ __align__(16) char smem[57344];
    f16*   Ab0 = (f16*)smem;             // [2][128*64] = 32 KB
    f16*   Bb0 = (f16*)(smem + 32768);   // [2][96*64] or [2][80*64]
    float* Sg  = (float*)smem;           // epilogue scoreboard (aliases staging)

    const int t   = threadIdx.x;
    const int L   = t & 63;
    const int w   = t >> 6;
    const int fr  = L & 15;
    const int fq  = L >> 4;
    const int rch = L >> 3;                       // row within 8-row chunk
    const int cs  = (((L & 7) ^ rch) << 3);       // swizzled source col (f16, <64)
    const int fsw = (fr & 7) << 3;                // frag-read swizzle (f16 units)
    const int nfB = ((fm + 127) >> 7) * 32;

    if ((int)blockIdx.x < nfB) {
        // ----------------- forward (leaves-to-root) tile -----------------
        const int by = blockIdx.x >> 5;
        const int bx = blockIdx.x & 31;
        const int wm = (w & 1) << 6;
        const int wn = (w >> 1) * 48;

        const f16* aLo[4]; const f16* aHi[4];
#pragma unroll
        for (int cc = 0; cc < 4; ++cc) {
            int g  = by * 128 + (w * 4 + cc) * 8 + rch;
            int n1 = ZROW, n2 = ZROW;
            if (g < fm) { n1 = lc[fbase + g]; n2 = rc[fbase + g]; }
            aLo[cc] = H + (size_t)n1 * 1024 + cs;
            aHi[cc] = H + (size_t)n2 * 1024 + cs - HDIM;
        }
        const f16* bsrc[3];
#pragma unroll
        for (int cc = 0; cc < 3; ++cc)
            bsrc[cc] = Wlr + (size_t)(bx * 96 + (w * 3 + cc) * 8 + rch) * 1024 + cs;

        f32x4 acc[4][3] = {};
#define STGF(sel, k0)                                                        \
        do {                                                                 \
            const bool hiK = (k0) >= HDIM;                                   \
            _Pragma("unroll")                                                \
            for (int cc = 0; cc < 4; ++cc)                                   \
                glds16((hiK ? aHi[cc] : aLo[cc]) + (k0),                     \
                       Ab0 + (sel) * 8192 + (w * 4 + cc) * 512 + L * 8);     \
            _Pragma("unroll")                                                \
            for (int cc = 0; cc < 3; ++cc)                                   \
                glds16(bsrc[cc] + (k0),                                      \
                       Bb0 + (sel) * 6144 + (w * 3 + cc) * 512 + L * 8);     \
        } while (0)

        STGF(0, 0);
        __syncthreads();
        int cur = 0;
        for (int tt = 0; tt < 16; ++tt) {
            if (tt + 1 < 16) STGF(cur ^ 1, (tt + 1) * 64);
            const f16* Ac = Ab0 + cur * 8192;
            const f16* Bc = Bb0 + cur * 6144;
            f16x8 af[4][2], bg[3][2];
#pragma unroll
            for (int i = 0; i < 4; ++i)
#pragma unroll
                for (int ks = 0; ks < 2; ++ks)
                    af[i][ks] = *(const f16x8*)(Ac + (wm + i * 16 + fr) * 64
                                + ((((ks * 4 + fq) << 3) ^ fsw)));
#pragma unroll
            for (int j = 0; j < 3; ++j)
#pragma unroll
                for (int ks = 0; ks < 2; ++ks)
                    bg[j][ks] = *(const f16x8*)(Bc + (wn + j * 16 + fr) * 64
                                + ((((ks * 4 + fq) << 3) ^ fsw)));
#pragma unroll
            for (int ks = 0; ks < 2; ++ks)
#pragma unroll
                for (int i = 0; i < 4; ++i)
#pragma unroll
                    for (int j = 0; j < 3; ++j)
                        acc[i][j] = __builtin_amdgcn_mfma_f32_16x16x32_f16(
                            af[i][ks], bg[j][ks], acc[i][j], 0, 0, 0);
            __syncthreads();
            cur ^= 1;
        }
#undef STGF
        // epilogue: acc -> Sg[128][100]
#pragma unroll
        for (int i = 0; i < 4; ++i)
#pragma unroll
            for (int j = 0; j < 3; ++j)
#pragma unroll
                for (int rr = 0; rr < 4; ++rr)
                    Sg[(wm + i * 16 + fq * 4 + rr) * 100 + wn + j * 16 + fr]
                        = acc[i][j][rr];
        __syncthreads();
        const int rmax = fm - by * 128;
        const int j0 = bx * 16;
        for (int cc = 0; cc < 8; ++cc) {
            int cell = t + cc * 256;
            int r = cell >> 4, j = cell & 15;
            if (r >= rmax) break;                 // r strictly increases with cc
            int node = fbase + by * 128 + r;
            int jj = j0 + j;
            const f16* pxr = PX + (size_t)node * NCAT;
            float g[6];
#pragma unroll
            for (int q = 0; q < 6; ++q)
                g[q] = (float)pxr[HDIM + q * HDIM + jj] + bl[q * HDIM + jj]
                     + br[q * HDIM + jj] + Sg[r * 100 + j * 6 + q];
            int lcn = lc[node], rcn = rc[node];
            float clv = cbf[(size_t)lcn * HDIM + jj];
            float crv = cbf[(size_t)rcn * HDIM + jj];
            float i_ = sigm(g[0]), o_ = sigm(g[1]), fl_ = sigm(g[2]), fr_ = sigm(g[3]);
            float u_ = tanhf(g[4]), r_ = sigm(g[5]);
            float c  = i_ * u_ + fl_ * clv + fr_ * crv;
            float hc = o_ * tanhf(c);
            float px = (float)pxr[jj];
            float hf = r_ * hc + (1.0f - r_) * px;
            cbf[(size_t)node * HDIM + jj] = c;
            H[(size_t)node * 1024 + jj] = (f16)hf;
            if (out32) out32[(size_t)node * 1024 + jj] = hf;
        }
    } else {
        // ----------------- backward (root-to-leaves) tile ----------------
        const int b2 = blockIdx.x - nfB;
        const int by = b2 >> 5;
        const int bx = b2 & 31;
        const int wm = w * 32;                    // 4 waves x 32 rows

        const f16* asrc[4];
#pragma unroll
        for (int cc = 0; cc < 4; ++cc) {
            int g = by * 128 + (w * 4 + cc) * 8 + rch;
            int n1 = ZROW;
            if (g < bm) n1 = par[bbase + g];
            asrc[cc] = H + (size_t)n1 * 1024 + HDIM + cs;
        }
        const f16* bsrc[3];
        int nbch[3];
#pragma unroll
        for (int cc = 0; cc < 3; ++cc) {
            int ch = w * 3 + cc;
            nbch[cc] = ch;
            bsrc[cc] = Wh + (size_t)(bx * 80 + ch * 8 + rch) * HDIM + cs;
        }

        f32x4 acc[2][5] = {};
#define STGB(sel, k0)                                                        \
        do {                                                                 \
            _Pragma("unroll")                                                \
            for (int cc = 0; cc < 4; ++cc)                                   \
                glds16(asrc[cc] + (k0),                                      \
                       Ab0 + (sel) * 8192 + (w * 4 + cc) * 512 + L * 8);     \
            _Pragma("unroll")                                                \
            for (int cc = 0; cc < 3; ++cc)                                   \
                if (nbch[cc] < 10)                                           \
                    glds16(bsrc[cc] + (k0),                                  \
                           Bb0 + (sel) * 5120 + nbch[cc] * 512 + L * 8);     \
        } while (0)

        STGB(0, 0);
        __syncthreads();
        int cur = 0;
        for (int tt = 0; tt < 8; ++tt) {
            if (tt + 1 < 8) STGB(cur ^ 1, (tt + 1) * 64);
            const f16* Ac = Ab0 + cur * 8192;
            const f16* Bc = Bb0 + cur * 5120;
            f16x8 af[2][2], bg[5][2];
#pragma unroll
            for (int i = 0; i < 2; ++i)
#pragma unroll
                for (int ks = 0; ks < 2; ++ks)
                    af[i][ks] = *(const f16x8*)(Ac + (wm + i * 16 + fr) * 64
                                + ((((ks * 4 + fq) << 3) ^ fsw)));
#pragma unroll
            for (int j = 0; j < 5; ++j)
#pragma unroll
                for (int ks = 0; ks < 2; ++ks)
                    bg[j][ks] = *(const f16x8*)(Bc + (j * 16 + fr) * 64
                                + ((((ks * 4 + fq) << 3) ^ fsw)));
#pragma unroll
            for (int ks = 0; ks < 2; ++ks)
#pragma unroll
                for (int i = 0; i < 2; ++i)
#pragma unroll
                    for (int j = 0; j < 5; ++j)
                        acc[i][j] = __builtin_amdgcn_mfma_f32_16x16x32_f16(
                            af[i][ks], bg[j][ks], acc[i][j], 0, 0, 0);
            __syncthreads();
            cur ^= 1;
        }
#undef STGB
#pragma unroll
        for (int i = 0; i < 2; ++i)
#pragma unroll
            for (int j = 0; j < 5; ++j)
#pragma unroll
                for (int rr = 0; rr < 4; ++rr)
                    Sg[(wm + i * 16 + fq * 4 + rr) * 84 + j * 16 + fr]
                        = acc[i][j][rr];
        __syncthreads();
        const int rmax = bm - by * 128;
        const int j0 = bx * 16;
        for (int cc = 0; cc < 8; ++cc) {
            int cell = t + cc * 256;
            int r = cell >> 4, j = cell & 15;
            if (r >= rmax) break;
            int node = bbase + by * 128 + r;
            int jj = j0 + j;
            const f16* pxr = PX + (size_t)node * NCAT;
            float g[5];
#pragma unroll
            for (int q = 0; q < 5; ++q)
                g[q] = (float)pxr[4096 + q * HDIM + jj] + bh[q * HDIM + jj]
                     + Sg[r * 84 + j * 5 + q];
            int p = par[node];
            float cp = cbb[(size_t)p * HDIM + jj];
            float i_ = sigm(g[0]), o_ = sigm(g[1]), f_ = sigm(g[2]);
            float u_ = tanhf(g[3]), r_ = sigm(g[4]);
            float c  = i_ * u_ + f_ * cp;
            float hc = o_ * tanhf(c);
            float px = (float)pxr[3584 + jj];
            float hf = r_ * hc + (1.0f - r_) * px;
            cbb[(size_t)node * HDIM + jj] = c;
            H[(size_t)node * 1024 + HDIM + jj] = (f16)hf;
            if (out32) out32[(size_t)node * 1024 + HDIM + jj] = hf;
        }
    }
}

// ---------------------------------------------------------------------------
// Elementwise for the no-GEMM cases only (fwd leaves + bwd root), vectorized.
// ---------------------------------------------------------------------------
__global__ __launch_bounds__(256) void elem_merged(
    const f16* __restrict__ PX,
    int fbase, int fm, int bbase, int bm,
    const int* __restrict__ lc, const int* __restrict__ rc,
    const int* __restrict__ par,
    float* __restrict__ cbf, float* __restrict__ cbb,
    f16* __restrict__ H, float* __restrict__ out32,
    const float* __restrict__ bl, const float* __restrict__ br,
    const float* __restrict__ bh)
{
    int t = blockIdx.x * 256 + threadIdx.x;
    const int fvec = fm * 64;               // HDIM/8 vectors per row
    if (t < fvec) {
        int row = t >> 6, j8 = (t & 63) << 3;
        int node = fbase + row;
        const f16* pxr = PX + (size_t)node * NCAT;
        float g[6][8];
#pragma unroll
        for (int q = 0; q < 6; ++q) {
            f16x8 pv = *(const f16x8*)(pxr + HDIM + q * HDIM + j8);
            const float* blp = bl + q * HDIM + j8;
            const float* brp = br + q * HDIM + j8;
#pragma unroll
            for (int e = 0; e < 8; ++e)
                g[q][e] = (float)pv[e] + blp[e] + brp[e];
        }
        int lcn = lc[node], rcn = rc[node];
        const float* clp = cbf + (size_t)lcn * HDIM + j8;
        const float* crp = cbf + (size_t)rcn * HDIM + j8;
        f32x4 cl0 = *(const f32x4*)clp, cl1 = *(const f32x4*)(clp + 4);
        f32x4 cr0 = *(const f32x4*)crp, cr1 = *(const f32x4*)(crp + 4);
        f16x8 pxv = *(const f16x8*)(pxr + j8);
        f32x4 co0, co1;
        f16x8 hv;
        f32x4 ho0, ho1;
#pragma unroll
        for (int e = 0; e < 8; ++e) {
            float clv = (e < 4) ? cl0[e & 3] : cl1[e & 3];
            float crv = (e < 4) ? cr0[e & 3] : cr1[e & 3];
            float i_ = sigm(g[0][e]), o_ = sigm(g[1][e]);
            float fl_ = sigm(g[2][e]), fr_ = sigm(g[3][e]);
            float u_ = tanhf(g[4][e]), r_ = sigm(g[5][e]);
            float c  = i_ * u_ + fl_ * clv + fr_ * crv;
            float hc = o_ * tanhf(c);
            float hf = r_ * hc + (1.0f - r_) * (float)pxv[e];
            if (e < 4) { co0[e & 3] = c; ho0[e & 3] = hf; }
            else       { co1[e & 3] = c; ho1[e & 3] = hf; }
            hv[e] = (f16)hf;
        }
        float* cdst = cbf + (size_t)node * HDIM + j8;
        *(f32x4*)cdst = co0; *(f32x4*)(cdst + 4) = co1;
        *(f16x8*)(H + (size_t)node * 1024 + j8) = hv;
        if (out32) {
            float* od = out32 + (size_t)node * 1024 + j8;
            *(f32x4*)od = ho0; *(f32x4*)(od + 4) = ho1;
        }
    } else {
        int t2 = t - fvec;
        if (t2 >= bm * 64) return;
        int row = t2 >> 6, j8 = (t2 & 63) << 3;
        int node = bbase + row;
        const f16* pxr = PX + (size_t)node * NCAT;
        float g[5][8];
#pragma unroll
        for (int q = 0; q < 5; ++q) {
            f16x8 pv = *(const f16x8*)(pxr + 4096 + q * HDIM + j8);
            const float* bhp = bh + q * HDIM + j8;
#pragma unroll
            for (int e = 0; e < 8; ++e)
                g[q][e] = (float)pv[e] + bhp[e];
        }
        int p = par[node];
        const float* cpp = cbb + (size_t)p * HDIM + j8;
        f32x4 cp0 = *(const f32x4*)cpp, cp1 = *(const f32x4*)(cpp + 4);
        f16x8 pxv = *(const f16x8*)(pxr + 3584 + j8);
        f32x4 co0, co1;
        f16x8 hv;
        f32x4 ho0, ho1;
#pragma unroll
        for (int e = 0; e < 8; ++e) {
            float cpv = (e < 4) ? cp0[e & 3] : cp1[e & 3];
            float i_ = sigm(g[0][e]), o_ = sigm(g[1][e]), f_ = sigm(g[2][e]);
            float u_ = tanhf(g[3][e]), r_ = sigm(g[4][e]);
            float c  = i_ * u_ + f_ * cpv;
            float hc = o_ * tanhf(c);
            float hf = r_ * hc + (1.0f - r_) * (float)pxv[e];
            if (e < 4) { co0[e & 3] = c; ho0[e & 3] = hf; }
            else       { co1[e & 3] = c; ho1[e & 3] = hf; }
            hv[e] = (f16)hf;
        }
        float* cdst = cbb + (size_t)node * HDIM + j8;
        *(f32x4*)cdst = co0; *(f32x4*)(cdst + 4) = co1;
        *(f16x8*)(H + (size_t)node * 1024 + HDIM + j8) = hv;
        if (out32) {
            float* od = out32 + (size_t)node * 1024 + HDIM + j8;
            *(f32x4*)od = ho0; *(f32x4*)(od + 4) = ho1;
        }
    }
}

extern "C" void kernel_launch(void* const* d_in, const int* in_sizes, int n_in,
                              void* d_out, int out_size, void* d_ws, size_t ws_size,
                              hipStream_t stream)
{
    (void)in_sizes; (void)n_in; (void)out_size; (void)ws_size;
    const float* features = (const float*)d_in[0];
    const float* fw_Wp = (const float*)d_in[1];
    const float* fw_bp = (const float*)d_in[2];
    const float* fw_Wx = (const float*)d_in[3];
    const float* fw_bx = (const float*)d_in[4];
    const float* fw_Wl = (const float*)d_in[5];
    const float* fw_bl = (const float*)d_in[6];
    const float* fw_Wr = (const float*)d_in[7];
    const float* fw_br = (const float*)d_in[8];
    const float* bw_Wp = (const float*)d_in[9];
    const float* bw_bp = (const float*)d_in[10];
    const float* bw_Wx = (const float*)d_in[11];
    const float* bw_bx = (const float*)d_in[12];
    const float* bw_Wh = (const float*)d_in[13];
    const float* bw_bh = (const float*)d_in[14];
    const int* lc  = (const int*)d_in[17];
    const int* rc  = (const int*)d_in[18];
    const int* par = (const int*)d_in[19];

    // workspace layout (f16 units unless noted), ~113 MB.
    f16* feat16 = (f16*)d_ws;                       // 4096*1024
    f16* H      = feat16 + (size_t)4096 * 1024;     // 4097*1024
    f16* Wcat   = H     + (size_t)4097 * 1024;      // 6656*1024
    f16* Wlr    = Wcat  + (size_t)NCAT * 1024;      // 3072*1024 (gate-interleaved)
    f16* Wh     = Wlr   + (size_t)3072 * 1024;      // 2560*512  (gate-interleaved)
    f16* PX     = Wh    + (size_t)2560 * 512;       // 4096*6656
    float* biascat = (float*)(PX + (size_t)4096 * NCAT);
    float* cbf     = biascat + NCAT;                // 4097*512 f32
    float* cbb     = cbf + (size_t)4097 * HDIM;     // 4097*512 f32

    zero_slots<<<dim3(1), dim3(1024), 0, stream>>>(H, cbf, cbb);
    cvt16<<<dim3(2048), 256, 0, stream>>>(features, feat16, 4096 * 1024 / 8);

    // stage schedule (per layer): merged launch i pairs fwd stage i with bwd
    // stage i. fwd: special node 2047, then levels 10..0. bwd: levels 1..12.
    static const int fb[12] = {2047, 1023, 511, 255, 127, 63, 31, 15, 7, 3, 1, 0};
    static const int fmv[12] = {1, 1024, 512, 256, 128, 64, 32, 16, 8, 4, 2, 1};
    static const int bb[12] = {1, 3, 7, 15, 31, 63, 127, 255, 511, 1023, 2047, 4095};
    static const int bmv[12] = {2, 4, 8, 16, 32, 64, 128, 256, 512, 1024, 2048, 1};

    for (int l = 0; l < 2; ++l) {
        cvt16<<<dim3(256),  256, 0, stream>>>(fw_Wp + (size_t)l * 512 * 1024,  Wcat,               512 * 1024 / 8);
        cvt16<<<dim3(1536), 256, 0, stream>>>(fw_Wx + (size_t)l * 3072 * 1024, Wcat + 512 * 1024,  3072 * 1024 / 8);
        cvt16<<<dim3(256),  256, 0, stream>>>(bw_Wp + (size_t)l * 512 * 1024,  Wcat + 3584 * 1024, 512 * 1024 / 8);
        cvt16<<<dim3(1280), 256, 0, stream>>>(bw_Wx + (size_t)l * 2560 * 1024, Wcat + (size_t)4096 * 1024, 2560 * 1024 / 8);
        cvt16_lr<<<dim3(1536), 256, 0, stream>>>(fw_Wl + (size_t)l * 3072 * 512,
                                                 fw_Wr + (size_t)l * 3072 * 512, Wlr);
        cvt16_perm5<<<dim3(640), 256, 0, stream>>>(bw_Wh + (size_t)l * 2560 * 512, Wh);
        biascat_k<<<dim3(26), 256, 0, stream>>>(fw_bp + (size_t)l * 512, fw_bx + (size_t)l * 3072,
                                                bw_bp + (size_t)l * 512, bw_bx + (size_t)l * 2560, biascat);

        // fused precompute: PX[4096][6656] = A @ [Wp_f|Wx_f|Wp_b|Wx_b]^T + bias
        const f16* A16 = (l == 0) ? feat16 : H;
        mm_pre<<<dim3(NCAT / 128, 4096 / 128), 256, 0, stream>>>(
            A16, Wcat, biascat, PX, NCAT, 1024);

        float* o32 = (l == 1) ? (float*)d_out : nullptr;
        const float* bl_l = fw_bl + (size_t)l * 3072;
        const float* br_l = fw_br + (size_t)l * 3072;
        const float* bh_l = bw_bh + (size_t)l * 2560;

        // merged leaves (fwd, m=2048) + root (bwd, m=1): no GEMM needed
        {
            int tot = (2048 + 1) * 64;
            elem_merged<<<dim3((tot + 255) / 256), 256, 0, stream>>>(
                PX, 2048, 2048, 0, 1,
                lc, rc, par, cbf, cbb, H, o32, bl_l, br_l, bh_l);
        }
        for (int i = 0; i < 12; ++i) {
            int nfB = ((fmv[i] + 127) >> 7) * 32;
            int nbB = ((bmv[i] + 127) >> 7) * 32;
            stage_fused<<<dim3(nfB + nbB), 256, 0, stream>>>(
                Wlr, Wh, H, PX, lc, rc, par,
                fb[i], fmv[i], bb[i], bmv[i],
                cbf, cbb, o32, bl_l, br_l, bh_l);
        }
    }
    // layer-1 stage/elem kernels wrote d_out directly; nothing else to copy
}